// Round 2
// baseline (128.689 us; speedup 1.0000x reference)
//
#include <hip/hip_runtime.h>
#include <math.h>

// Chamfer loss, B=4, C=3, Np=Ng=8192, fp32.
// Round 6: atomic-free restructure. R1 post-mortem showed the device-scope
// atomicMin publish costs ~6 ns/op (WRITE_SIZE tracks atomic count 1:1; +2.1M
// atomics => +13 us) and the epilogue vmcnt drain pins occupancy at ~2
// waves/SIMD. New structure: 4 dispatches, zero global atomics, zero barriers
// in the sweep, stream order as the only sync.
//   K0: pack y-records (x0,x1,y0,y1,z0,z1,g2_0,g2_1) for both passes -> ws (1MB)
//   K1: sweep, grid (16,16,8)=2048 wgs, RX=2, uniform packed loads (broadcast),
//       depth-2 register pipeline, plain coalesced partial-min stores (4MB)
//   K2: 16-way min + sqrt + block tree-sum -> gsum2[256]
//   K3: deterministic final tree-sum -> out
// Gated on ws_size >= ~5.25MB; falls back to the known-good R0 single-dispatch
// atomic kernel otherwise (needs only 257KB).

#define B_       4
#define N_       8192
#define THREADS  256

typedef float v2f __attribute__((ext_vector_type(2)));

__device__ __forceinline__ v2f pk_fma(v2f a, v2f b, v2f c) {
    v2f d;
    asm("v_pk_fma_f32 %0, %1, %2, %3" : "=v"(d) : "v"(a), "v"(b), "v"(c));
    return d;
}

// ---------------- primary path (atomic-free) ----------------
#define RX1      2
#define XB1      (THREADS * RX1)       // 512 x-points per wg
#define XBLKS1   (N_ / XB1)            // 16
#define YSPL1    16
#define YREC     (N_ / 2 / YSPL1)      // 256 pair-records per y-split
#define NPB      (2 * B_)              // 8 (pass,b) slabs
#define NREC_PB  (N_ / 2)              // 4096 records per slab

// ws word layout (primary):
//   packed : [0, 262144)        NPB * 4096 records * 8 floats  (1 MB)
//   partial: [262144, 1310720)  NPB * YSPL1 * 8192 floats      (4 MB)
//   gsum2  : [1310720, 1310976) 256 floats
#define OFF_PACKED   0
#define OFF_PARTIAL  262144
#define OFF_GSUM2    1310720
#define WORDS_NEED   1310976

// K0: build packed y-pair records for both sweep directions.
// record j of slab pb=(pass*4+b): points 2j, 2j+1 of Y (pass0: Y=G, pass1: Y=P).
__global__ __launch_bounds__(THREADS)
void chamfer_pack_kernel(const float* __restrict__ P, const float* __restrict__ G,
                         float4* __restrict__ packed)
{
    const int g  = blockIdx.x * THREADS + threadIdx.x;   // [0, 32768)
    const int pb = g >> 12;                              // 0..7
    const int j  = g & 4095;
    const int pass = pb >> 2, b = pb & 3;
    const float* Yb = (pass ? P : G) + (size_t)b * 3 * N_;
    const int n0 = 2 * j;
    float2 x01 = *(const float2*)&Yb[n0];
    float2 y01 = *(const float2*)&Yb[N_ + n0];
    float2 z01 = *(const float2*)&Yb[2 * N_ + n0];
    float w0 = fmaf(x01.x, x01.x, fmaf(y01.x, y01.x, z01.x * z01.x));
    float w1 = fmaf(x01.y, x01.y, fmaf(y01.y, y01.y, z01.y * z01.y));
    packed[2 * (size_t)g]     = make_float4(x01.x, x01.y, y01.x, y01.y);
    packed[2 * (size_t)g + 1] = make_float4(z01.x, z01.y, w0, w1);
}

// K1: sweep. No LDS, no barriers, no atomics. Packed loads are wave-uniform
// (jj + block-derived base) -> single broadcast transaction / SMEM-promotable.
__global__ __launch_bounds__(THREADS)
void chamfer_sweep_kernel(const float* __restrict__ P, const float* __restrict__ G,
                          const float4* __restrict__ packed,
                          float* __restrict__ partial)
{
    const int t      = threadIdx.x;
    const int xblk   = blockIdx.x;     // 0..15
    const int ysplit = blockIdx.y;     // 0..15
    const int bz     = blockIdx.z;     // 0..7
    const int pass   = bz >> 2;
    const int b      = bz & 3;

    const float* Xb = (pass ? G : P) + (size_t)b * 3 * N_;
    const int xbase = xblk * XB1;

    v2f m2x2[RX1], m2y2[RX1], m2z2[RX1];
    float p2[RX1], mn[RX1];
#pragma unroll
    for (int r = 0; r < RX1; ++r) {
        const int n = xbase + r * THREADS + t;
        float px = Xb[n];
        float py = Xb[N_ + n];
        float pz = Xb[2 * N_ + n];
        p2[r]   = fmaf(px, px, fmaf(py, py, pz * pz));
        float ax = -2.0f * px, ay = -2.0f * py, az = -2.0f * pz;
        m2x2[r] = (v2f){ax, ax};
        m2y2[r] = (v2f){ay, ay};
        m2z2[r] = (v2f){az, az};
        mn[r]   = 3.4e38f;
    }

    // This split's 256 records. Depth-2 register pipeline; the prefetch
    // overreads up to 64B past the last slab's records — lands in the
    // partial region (valid ws memory), values rotated in but never used.
    const float4* rec = packed + 2 * ((size_t)bz * NREC_PB + ysplit * YREC);
    float4 a0 = rec[0], b0 = rec[1];
    float4 a1 = rec[2], b1 = rec[3];
#pragma unroll 2
    for (int jj = 0; jj < YREC; ++jj) {
        float4 an = rec[2 * jj + 4];
        float4 bn = rec[2 * jj + 5];
        v2f gx2 = (v2f){a0.x, a0.y};
        v2f gy2 = (v2f){a0.z, a0.w};
        v2f gz2 = (v2f){b0.x, b0.y};
        v2f gw2 = (v2f){b0.z, b0.w};
#pragma unroll
        for (int r = 0; r < RX1; ++r) {
            v2f s = pk_fma(m2z2[r], gz2, gw2);
            s = pk_fma(m2y2[r], gy2, s);
            s = pk_fma(m2x2[r], gx2, s);
            mn[r] = fminf(fminf(mn[r], s.x), s.y);   // -> v_min3_f32
        }
        a0 = a1; b0 = b1; a1 = an; b1 = bn;
    }

    // Plain coalesced stores of clamped partial d2 (order vs other wgs
    // irrelevant: disjoint slots).
    float* pout = partial + ((size_t)bz * YSPL1 + ysplit) * N_ + xbase;
#pragma unroll
    for (int r = 0; r < RX1; ++r)
        pout[r * THREADS + t] = fmaxf(mn[r] + p2[r], 1e-12f);
}

// K2: per x-slot: min over YSPL1 partials, sqrt, block tree-sum.
__global__ __launch_bounds__(THREADS)
void chamfer_reduce1_kernel(const float* __restrict__ partial,
                            float* __restrict__ gsum2)
{
    __shared__ float red[THREADS];
    const int g  = blockIdx.x * THREADS + threadIdx.x;   // [0, 65536)
    const int pb = g >> 13;
    const int x  = g & 8191;
    const float* p = partial + (size_t)pb * YSPL1 * N_ + x;
    float m = p[0];
#pragma unroll
    for (int ys = 1; ys < YSPL1; ++ys)
        m = fminf(m, p[(size_t)ys * N_]);
    red[threadIdx.x] = sqrtf(m);
    __syncthreads();
    for (int off = 128; off > 0; off >>= 1) {
        if (threadIdx.x < off) red[threadIdx.x] += red[threadIdx.x + off];
        __syncthreads();
    }
    if (threadIdx.x == 0) gsum2[blockIdx.x] = red[0];
}

// K3: deterministic final sum of 256 block sums.
__global__ __launch_bounds__(THREADS)
void chamfer_final_kernel(const float* __restrict__ gsum2, float* __restrict__ out)
{
    __shared__ float red[THREADS];
    red[threadIdx.x] = gsum2[threadIdx.x];
    __syncthreads();
    for (int off = 128; off > 0; off >>= 1) {
        if (threadIdx.x < off) red[threadIdx.x] += red[threadIdx.x + off];
        __syncthreads();
    }
    if (threadIdx.x == 0) out[0] = red[0] * (1.0f / 65536.0f);   // denom = B*(Ng+Np)
}

// ---------------- fallback path (known-good R0, 257KB ws) ----------------
#define LRX      8
#define LXB      (THREADS * LRX)       // 2048
#define LXBLKS   (N_ / LXB)            // 4
#define LYSPL    32
#define LYCHUNK  (N_ / LYSPL)          // 256
#define LNGROUPS (2 * B_ * LXBLKS)     // 32
#define POISON   0xAAAAAAAAu

__global__ __launch_bounds__(THREADS)
void chamfer_fused_kernel(const float* __restrict__ P, const float* __restrict__ G,
                          unsigned* __restrict__ mins, unsigned* __restrict__ gcnt,
                          unsigned* __restrict__ fcnt, float* __restrict__ gsum,
                          float* __restrict__ out)
{
    __shared__ float4 ytile[2 * (LYCHUNK / 2)];
    __shared__ float red[THREADS];
    __shared__ unsigned s_ticket;

    const int t      = threadIdx.x;
    const int xblk   = blockIdx.x;
    const int ysplit = blockIdx.y;
    const int bz     = blockIdx.z;
    const int pass   = bz >> 2;
    const int b      = bz & 3;
    const int gid    = bz * LXBLKS + xblk;

    const float* Xb = (pass ? G : P) + (size_t)b * 3 * N_;
    const float* Yb = (pass ? P : G) + (size_t)b * 3 * N_;

    const int ybase = ysplit * LYCHUNK;
    if (t < LYCHUNK / 2) {
        const int n0 = ybase + 2 * t;
        float2 x01 = *(const float2*)&Yb[n0];
        float2 y01 = *(const float2*)&Yb[N_ + n0];
        float2 z01 = *(const float2*)&Yb[2 * N_ + n0];
        float w0 = fmaf(x01.x, x01.x, fmaf(y01.x, y01.x, z01.x * z01.x));
        float w1 = fmaf(x01.y, x01.y, fmaf(y01.y, y01.y, z01.y * z01.y));
        ytile[2 * t]     = make_float4(x01.x, x01.y, y01.x, y01.y);
        ytile[2 * t + 1] = make_float4(z01.x, z01.y, w0, w1);
    }

    const int xbase = xblk * LXB;
    v2f m2x2[LRX], m2y2[LRX], m2z2[LRX];
    float p2[LRX], mn[LRX];
#pragma unroll
    for (int r = 0; r < LRX; ++r) {
        const int n = xbase + r * THREADS + t;
        float px = Xb[n];
        float py = Xb[N_ + n];
        float pz = Xb[2 * N_ + n];
        p2[r]   = fmaf(px, px, fmaf(py, py, pz * pz));
        float ax = -2.0f * px, ay = -2.0f * py, az = -2.0f * pz;
        m2x2[r] = (v2f){ax, ax};
        m2y2[r] = (v2f){ay, ay};
        m2z2[r] = (v2f){az, az};
        mn[r]   = 3.4e38f;
    }
    __syncthreads();

#pragma unroll 2
    for (int jj = 0; jj < LYCHUNK / 2; ++jj) {
        float4 a4 = ytile[2 * jj];
        float4 b4 = ytile[2 * jj + 1];
        v2f gx2 = (v2f){a4.x, a4.y};
        v2f gy2 = (v2f){a4.z, a4.w};
        v2f gz2 = (v2f){b4.x, b4.y};
        v2f gw2 = (v2f){b4.z, b4.w};
#pragma unroll
        for (int r = 0; r < LRX; ++r) {
            v2f s = pk_fma(m2z2[r], gz2, gw2);
            s = pk_fma(m2y2[r], gy2, s);
            s = pk_fma(m2x2[r], gx2, s);
            mn[r] = fminf(fminf(mn[r], s.x), s.y);
        }
    }

    unsigned* mybase = mins + (size_t)(pass * B_ + b) * N_ + xbase;
#pragma unroll
    for (int r = 0; r < LRX; ++r) {
        float v = fmaxf(mn[r] + p2[r], 1e-12f);
        atomicMin(&mybase[r * THREADS + t], __float_as_uint(v));
    }

    __syncthreads();
    if (t == 0) {
        __threadfence();
        s_ticket = atomicAdd(&gcnt[gid], 1u);
    }
    __syncthreads();
    if (s_ticket != POISON + (unsigned)(LYSPL - 1)) return;

    __threadfence();
    const uint4* vmin = (const uint4*)(mins + (size_t)(pass * B_ + b) * N_ + xbase);
    uint4 q0 = vmin[t];
    uint4 q1 = vmin[THREADS + t];
    float a = sqrtf(__uint_as_float(q0.x)) + sqrtf(__uint_as_float(q0.y))
            + sqrtf(__uint_as_float(q0.z)) + sqrtf(__uint_as_float(q0.w))
            + sqrtf(__uint_as_float(q1.x)) + sqrtf(__uint_as_float(q1.y))
            + sqrtf(__uint_as_float(q1.z)) + sqrtf(__uint_as_float(q1.w));
    red[t] = a;
    __syncthreads();
    for (int off = 128; off > 0; off >>= 1) {
        if (t < off) red[t] += red[t + off];
        __syncthreads();
    }
    if (t == 0) {
        gsum[gid] = red[0];
        __threadfence();
        s_ticket = atomicAdd(fcnt, 1u);
    }
    __syncthreads();
    if (s_ticket != POISON + (unsigned)(LNGROUPS - 1)) return;

    __threadfence();
    red[t] = (t < LNGROUPS) ? gsum[t] : 0.0f;
    __syncthreads();
    for (int off = 128; off > 0; off >>= 1) {
        if (t < off) red[t] += red[t + off];
        __syncthreads();
    }
    if (t == 0) out[0] = red[0] * (1.0f / 65536.0f);
}

extern "C" void kernel_launch(void* const* d_in, const int* in_sizes, int n_in,
                              void* d_out, int out_size, void* d_ws, size_t ws_size,
                              hipStream_t stream)
{
    const float* P = (const float*)d_in[0];   // predict_pc [4,3,8192]
    const float* G = (const float*)d_in[1];   // gt_pc      [4,3,8192]
    float* out = (float*)d_out;               // scalar

    if (ws_size >= (size_t)WORDS_NEED * 4) {
        float*  wsf     = (float*)d_ws;
        float4* packed  = (float4*)(wsf + OFF_PACKED);
        float*  partial = wsf + OFF_PARTIAL;
        float*  gsum2   = wsf + OFF_GSUM2;
        chamfer_pack_kernel<<<dim3(128), THREADS, 0, stream>>>(P, G, packed);
        chamfer_sweep_kernel<<<dim3(XBLKS1, YSPL1, 2 * B_), THREADS, 0, stream>>>(P, G, packed, partial);
        chamfer_reduce1_kernel<<<dim3(256), THREADS, 0, stream>>>(partial, gsum2);
        chamfer_final_kernel<<<dim3(1), THREADS, 0, stream>>>(gsum2, out);
    } else {
        unsigned* w    = (unsigned*)d_ws;
        unsigned* mins = w;                   // 65536 words
        unsigned* gcnt = w + 65536;           // 32 words
        unsigned* fcnt = w + 65600;           // 1 word
        float*    gsum = (float*)(w + 65664); // 32 words
        dim3 grid(LXBLKS, LYSPL, 2 * B_);
        chamfer_fused_kernel<<<grid, THREADS, 0, stream>>>(P, G, mins, gcnt, fcnt, gsum, out);
    }
}